// Round 1
// baseline (39.527 us; speedup 1.0000x reference)
//
#include <hip/hip_runtime.h>
#include <math.h>

constexpr int BATCH = 4096;
constexpr int DIM   = 2048;
constexpr int REPS  = 8;
constexpr float INV2PI = 0.15915494309189535f;  // 1/(2*pi)

constexpr int TPB    = 256;            // threads per block (span d)
constexpr int GRIDX  = DIM / TPB;      // 8
constexpr int GRIDY  = 128;            // batch split
constexpr int BPB    = BATCH / GRIDY;  // 32 batch rows per block
constexpr int ILP    = 4;              // batch elements in flight per thread

__global__ __launch_bounds__(TPB, 4)
void daruan_bloch_kernel(const float* __restrict__ x,       // (BATCH, DIM)
                         const float* __restrict__ theta,   // (DIM, REPS+1, 2)
                         const float* __restrict__ paw,     // (DIM, REPS)
                         const float* __restrict__ pab,     // (DIM, REPS)
                         const float* __restrict__ postw,   // (DIM)
                         const float* __restrict__ postb,   // (DIM)
                         float* __restrict__ out)           // (BATCH, DIM)
{
    const int d = blockIdx.x * TPB + threadIdx.x;   // 0..DIM-1, coalesced over lanes

    // ---- per-d preamble: trainable rotation sin/cos (full angles, Bloch form) ----
    float c0[REPS + 1], s0[REPS + 1], c1[REPS + 1], s1[REPS + 1];
    const float* th = theta + (size_t)d * (REPS + 1) * 2;
#pragma unroll
    for (int r = 0; r <= REPS; ++r) {
        const float t0 = th[2 * r + 0] * INV2PI;   // revolutions for v_sin/v_cos
        const float t1 = th[2 * r + 1] * INV2PI;
        c0[r] = __builtin_amdgcn_cosf(t0);
        s0[r] = __builtin_amdgcn_sinf(t0);
        c1[r] = __builtin_amdgcn_cosf(t1);
        s1[r] = __builtin_amdgcn_sinf(t1);
    }
    float wr[REPS], br[REPS];
#pragma unroll
    for (int r = 0; r < REPS; ++r) {
        wr[r] = paw[(size_t)d * REPS + r] * INV2PI;  // fold 1/2pi: hw sincos takes revolutions
        br[r] = pab[(size_t)d * REPS + r] * INV2PI;
    }
    const float pwd = postw[d];
    const float pbd = postb[d];

    const int bbase = blockIdx.y * BPB;

    for (int bb = 0; bb < BPB; bb += ILP) {
        float xv[ILP];
#pragma unroll
        for (int i = 0; i < ILP; ++i)
            xv[i] = x[(size_t)(bbase + bb + i) * DIM + d];

        float X[ILP], Y[ILP], Z[ILP];
#pragma unroll
        for (int i = 0; i < ILP; ++i) { X[i] = 1.0f; Y[i] = 0.0f; Z[i] = 0.0f; }

#pragma unroll
        for (int r = 0; r < REPS; ++r) {
#pragma unroll
            for (int i = 0; i < ILP; ++i) {
                // RZ(theta0): rotate (X,Y) by full angle
                float Xa = X[i] * c0[r] - Y[i] * s0[r];
                float Ya = X[i] * s0[r] + Y[i] * c0[r];
                // RY(theta1): rotate (X,Z): X' = cX + sZ, Z' = cZ - sX
                float Xb = Xa * c1[r] + Z[i] * s1[r];
                float Zb = Z[i] * c1[r] - Xa * s1[r];
                // RZ(encoded): angle_rev = (w/2pi)*x + b/2pi
                const float erev = wr[r] * xv[i] + br[r];
                const float ce = __builtin_amdgcn_cosf(erev);
                const float se = __builtin_amdgcn_sinf(erev);
                X[i] = Xb * ce - Ya * se;
                Y[i] = Xb * se + Ya * ce;
                Z[i] = Zb;
            }
        }

#pragma unroll
        for (int i = 0; i < ILP; ++i) {
            // final RZ then RY; only Z survives the readout
            const float Xf = X[i] * c0[REPS] - Y[i] * s0[REPS];
            const float Zf = Z[i] * c1[REPS] - Xf * s1[REPS];
            out[(size_t)(bbase + bb + i) * DIM + d] = Zf * pwd + pbd;
        }
    }
}

extern "C" void kernel_launch(void* const* d_in, const int* in_sizes, int n_in,
                              void* d_out, int out_size, void* d_ws, size_t ws_size,
                              hipStream_t stream) {
    const float* x     = (const float*)d_in[0];
    const float* theta = (const float*)d_in[1];
    const float* paw   = (const float*)d_in[2];
    const float* pab   = (const float*)d_in[3];
    const float* postw = (const float*)d_in[4];
    const float* postb = (const float*)d_in[5];
    float* out = (float*)d_out;

    dim3 grid(GRIDX, GRIDY);
    dim3 block(TPB);
    daruan_bloch_kernel<<<grid, block, 0, stream>>>(x, theta, paw, pab, postw, postb, out);
}

// Round 2
// 32.506 us; speedup vs baseline: 1.2160x; 1.2160x over previous
//
#include <hip/hip_runtime.h>
#include <math.h>

constexpr int BATCH = 4096;
constexpr int DIM   = 2048;
constexpr int REPS  = 8;
constexpr float INV2PI = 0.15915494309189535f;  // 1/(2*pi)

constexpr int TPB    = 256;            // threads per block (span d)
constexpr int GRIDX  = DIM / TPB;      // 8
constexpr int GRIDY  = 256;            // batch split -> 2048 blocks = 8192 waves (100% slots)
constexpr int BPB    = BATCH / GRIDY;  // 16 batch rows per block
constexpr int ILP    = 4;              // batch elements in flight per thread

__global__ __launch_bounds__(TPB, 8)
void daruan_bloch_kernel(const float* __restrict__ x,       // (BATCH, DIM)
                         const float* __restrict__ theta,   // (DIM, REPS+1, 2)
                         const float* __restrict__ paw,     // (DIM, REPS)
                         const float* __restrict__ pab,     // (DIM, REPS)
                         const float* __restrict__ postw,   // (DIM)
                         const float* __restrict__ postb,   // (DIM)
                         float* __restrict__ out)           // (BATCH, DIM)
{
    const int d = blockIdx.x * TPB + threadIdx.x;   // coalesced over lanes

    // ---- per-d preamble ----
    // Trainable RZ folding: every RZ(theta0[r]) for r>=1 (incl. the final one)
    // is a Z-rotation immediately after the previous rep's encoded Z-rotation,
    // so its angle is absorbed into that rep's encoding bias. The first
    // RZ(theta0[0]) acts on Bloch state (1,0,0) -> (cos t00, sin t00, 0).
    const float* th = theta + (size_t)d * (REPS + 1) * 2;

    const float t00 = th[0] * INV2PI;
    const float X0 = __builtin_amdgcn_cosf(t00);
    const float Y0 = __builtin_amdgcn_sinf(t00);

    float c1[REPS + 1], s1[REPS + 1];
#pragma unroll
    for (int r = 0; r <= REPS; ++r) {
        const float t1 = th[2 * r + 1] * INV2PI;
        c1[r] = __builtin_amdgcn_cosf(t1);
        s1[r] = __builtin_amdgcn_sinf(t1);
    }
    float wr[REPS], brf[REPS];
#pragma unroll
    for (int r = 0; r < REPS; ++r) {
        wr[r]  = paw[(size_t)d * REPS + r] * INV2PI;
        // fold next trainable RZ angle theta0[r+1] into this rep's bias
        brf[r] = (pab[(size_t)d * REPS + r] + th[2 * (r + 1)]) * INV2PI;
    }
    const float pwd = postw[d];
    const float pbd = postb[d];

    const int bbase = blockIdx.y * BPB;

    for (int bb = 0; bb < BPB; bb += ILP) {
        float xv[ILP];
#pragma unroll
        for (int i = 0; i < ILP; ++i)
            xv[i] = x[(size_t)(bbase + bb + i) * DIM + d];

        float X[ILP], Y[ILP], Z[ILP];
#pragma unroll
        for (int i = 0; i < ILP; ++i) { X[i] = X0; Y[i] = Y0; Z[i] = 0.0f; }

#pragma unroll
        for (int r = 0; r < REPS; ++r) {
#pragma unroll
            for (int i = 0; i < ILP; ++i) {
                // RY(theta1[r]): rotate (X,Z)
                const float Xb = X[i] * c1[r] + Z[i] * s1[r];
                const float Zb = Z[i] * c1[r] - X[i] * s1[r];
                // encoded RZ (with folded trainable RZ of next rep)
                const float erev = wr[r] * xv[i] + brf[r];
                const float ce = __builtin_amdgcn_cosf(erev);
                const float se = __builtin_amdgcn_sinf(erev);
                X[i] = Xb * ce - Y[i] * se;
                Y[i] = Xb * se + Y[i] * ce;
                Z[i] = Zb;
            }
        }

#pragma unroll
        for (int i = 0; i < ILP; ++i) {
            // final RY; only Z survives the <Z> readout
            const float Zf = Z[i] * c1[REPS] - X[i] * s1[REPS];
            out[(size_t)(bbase + bb + i) * DIM + d] = Zf * pwd + pbd;
        }
    }
}

extern "C" void kernel_launch(void* const* d_in, const int* in_sizes, int n_in,
                              void* d_out, int out_size, void* d_ws, size_t ws_size,
                              hipStream_t stream) {
    const float* x     = (const float*)d_in[0];
    const float* theta = (const float*)d_in[1];
    const float* paw   = (const float*)d_in[2];
    const float* pab   = (const float*)d_in[3];
    const float* postw = (const float*)d_in[4];
    const float* postb = (const float*)d_in[5];
    float* out = (float*)d_out;

    dim3 grid(GRIDX, GRIDY);
    dim3 block(TPB);
    daruan_bloch_kernel<<<grid, block, 0, stream>>>(x, theta, paw, pab, postw, postb, out);
}